// Round 15
// baseline (38.749 us; speedup 1.0000x reference)
//
#include <hip/hip_runtime.h>

typedef _Float16 hh2 __attribute__((ext_vector_type(2)));

#define DH 40
#define DW 40
#define DT 40
#define NC 96
#define NH 6
#define HD 16
#define NTOK 27
#define NVOX (DH * DW * DT)

#define TX 8
#define TY 4
#define TZ 8
#define HX 10
#define HY 6
#define HZ 10
#define NHALO 600

#define NTILE 250
#define NBLK 750               // 250 tiles x 3 head-pairs; 2 jobs (heads) each
#define GRID 752
#define PER_XCD 94

__device__ __forceinline__ float dot2acc(hh2 a, hh2 b, float c) {
    return __builtin_amdgcn_fdot2(a, b, c, false);
}
__device__ __forceinline__ unsigned int pkbits(float a, float b) {
    return __builtin_bit_cast(unsigned int, __builtin_amdgcn_cvt_pkrtz(a, b));
}
__device__ __forceinline__ hh2 asz(unsigned int u) {
    return __builtin_bit_cast(hh2, u);
}

union I4H {
    int4 v[2];
    hh2 h[8];
};

// 3 waves/EU -> VGPR cap ~170 (10 in-flight float4 + q regs fit, no spill);
// LDS 38.4 KB double buffer -> 4 blocks/CU, avg residency is 2.9.
__global__ __launch_bounds__(256, 3) void natt_disp_kernel(
    const float* __restrict__ q,
    const float* __restrict__ k,
    const float* __restrict__ rpb,
    float* __restrict__ out)
{
    // Two halo buffers (job A / job B). Dense 32B rows, 16B chunks
    // parity-XOR'd by hy&1 (R8/R14 layout, measured conflict-neutral).
    __shared__ int4 s_k[2][NHALO * 2];   // 38.4 KB

    const int sb = (blockIdx.x & 7) * PER_XCD + (blockIdx.x >> 3);
    if (sb >= NBLK) return;    // block-uniform, before any sync

    const int hp   = sb % 3;             // head pair -> heads 2hp, 2hp+1
    const int tile = sb / 3;
    const int tz = tile % 5;
    const int ty = (tile / 5) % 10;
    const int tx = tile / 50;
    const int x0 = tx * TX, y0 = ty * TY, z0 = tz * TZ;

    const int tid = threadIdx.x;
    const int lz = tid & 7;
    const int ly = (tid >> 3) & 3;
    const int lx = tid >> 5;
    const int vox = ((x0 + lx) * DW + (y0 + ly)) * DT + (z0 + lz);

    const int h0 = 2 * hp, h1 = 2 * hp + 1;

    // ---- rpb both heads: block-uniform -> SGPRs; LOG2E folded ----
    const float LOG2E = 1.44269504f;
    float rk0[NTOK], rk1[NTOK];
    {
        const float* rb = rpb + h0 * NTOK;
        #pragma unroll
        for (int kk = 0; kk < NTOK; ++kk) rk0[kk] = rb[kk] * LOG2E;
        #pragma unroll
        for (int kk = 0; kk < NTOK; ++kk) rk1[kk] = rb[NTOK + kk] * LOG2E;
    }

    const float* kh0 = k + h0 * HD;
    const float* kh1 = k + h1 * HD;

    // ================= stage job A (head h0) into buf0 =================
    // 4-lane coop: lanes 4n..4n+3 read voxel n's 64B contiguously.
    #pragma unroll
    for (int it = 0; it < 10; ++it) {
        const int jj = tid + it * 256;
        if (jj < NHALO * 4) {
            const int n = jj >> 2;
            const int c = jj & 3;
            const int hx = n / (HY * HZ);
            const int r  = n - hx * (HY * HZ);
            const int hy = r / HZ;
            const int hz = r - hy * HZ;
            const int gx = x0 - 1 + hx;
            const int gy = y0 - 1 + hy;
            const int gz = z0 - 1 + hz;
            uint2 w; w.x = 0u; w.y = 0u;
            if (((unsigned)gx < DH) & ((unsigned)gy < DW) & ((unsigned)gz < DT)) {
                const float4 a = *(const float4*)(
                    kh0 + ((size_t)((gx * DW + gy) * DT + gz)) * NC + c * 4);
                w.x = pkbits(a.x, a.y);
                w.y = pkbits(a.z, a.w);
            }
            ((uint2*)s_k[0])[((n * 2 + (c >> 1)) ^ (hy & 1)) * 2 + (c & 1)] = w;
        }
    }

    // q for job A (direct per-thread; consumed immediately)
    hh2 qhA[8];
    {
        const float4* qv = (const float4*)(q + (size_t)vox * NC + h0 * HD);
        const float4 a = qv[0], b = qv[1], c = qv[2], d = qv[3];
        qhA[0] = asz(pkbits(a.x, a.y)); qhA[1] = asz(pkbits(a.z, a.w));
        qhA[2] = asz(pkbits(b.x, b.y)); qhA[3] = asz(pkbits(b.z, b.w));
        qhA[4] = asz(pkbits(c.x, c.y)); qhA[5] = asz(pkbits(c.z, c.w));
        qhA[6] = asz(pkbits(d.x, d.y)); qhA[7] = asz(pkbits(d.z, d.w));
    }

    __syncthreads();

    // ============ issue job B loads (head h1) — no waits here ==========
    // Same tile, adjacent head: same 128B lines as job A -> L1-hot.
    float4 FB[10];
    #pragma unroll
    for (int it = 0; it < 10; ++it) FB[it] = make_float4(0.f, 0.f, 0.f, 0.f);
    #pragma unroll
    for (int it = 0; it < 10; ++it) {
        const int jj = tid + it * 256;
        if (jj < NHALO * 4) {
            const int n = jj >> 2;
            const int c = jj & 3;
            const int hx = n / (HY * HZ);
            const int r  = n - hx * (HY * HZ);
            const int hy = r / HZ;
            const int hz = r - hy * HZ;
            const int gx = x0 - 1 + hx;
            const int gy = y0 - 1 + hy;
            const int gz = z0 - 1 + hz;
            if (((unsigned)gx < DH) & ((unsigned)gy < DW) & ((unsigned)gz < DT)) {
                FB[it] = *(const float4*)(
                    kh1 + ((size_t)((gx * DW + gy) * DT + gz)) * NC + c * 4);
            }
        }
    }
    float4 QB0, QB1, QB2, QB3;
    {
        const float4* qv = (const float4*)(q + (size_t)vox * NC + h1 * HD);
        QB0 = qv[0]; QB1 = qv[1]; QB2 = qv[2]; QB3 = qv[3];
    }
    __builtin_amdgcn_sched_barrier(0);   // pin B-load issue before compute A

    // fused compute: dot -> exp2 (no max; |logit|max ~5.6 << fp32 range) ->
    // 4-accumulator displacement.
    const float SC2 = 0.36067376f;       // 0.25 * LOG2E
    auto compute = [&](const int4* buf, hh2 (&qh)[8], float (&rk)[NTOK],
                       int hh) {
        float sum = 0.f, sx = 0.f, sy = 0.f, sz = 0.f;
        #pragma unroll
        for (int i = 0; i < 3; ++i) {
            #pragma unroll
            for (int j = 0; j < 3; ++j) {
                const int base = ((lx + i) * HY + (ly + j)) * HZ + lz;
                const int p = (ly + j) & 1;
                #pragma unroll
                for (int ll = 0; ll < 3; ++ll) {
                    const int n = base + ll;
                    I4H u;
                    u.v[0] = buf[(n * 2 + 0) ^ p];
                    u.v[1] = buf[(n * 2 + 1) ^ p];
                    float d = 0.0f;
                    d = dot2acc(qh[0], u.h[0], d);
                    d = dot2acc(qh[1], u.h[1], d);
                    d = dot2acc(qh[2], u.h[2], d);
                    d = dot2acc(qh[3], u.h[3], d);
                    d = dot2acc(qh[4], u.h[4], d);
                    d = dot2acc(qh[5], u.h[5], d);
                    d = dot2acc(qh[6], u.h[6], d);
                    d = dot2acc(qh[7], u.h[7], d);
                    const int kk = (i * 3 + j) * 3 + ll;
                    const float t = exp2f(fmaf(d, SC2, rk[kk]));
                    sum += t;
                    if (i == 0) sx -= t; else if (i == 2) sx += t;
                    if (j == 0) sy -= t; else if (j == 2) sy += t;
                    if (ll == 0) sz -= t; else if (ll == 2) sz += t;
                }
            }
        }
        const float inv = __builtin_amdgcn_rcpf(sum);
        out[((size_t)(hh * 3 + 0)) * NVOX + vox] = sx * inv;
        out[((size_t)(hh * 3 + 1)) * NVOX + vox] = sy * inv;
        out[((size_t)(hh * 3 + 2)) * NVOX + vox] = sz * inv;
    };

    // ================= compute job A (overlaps B's loads) ==============
    compute(s_k[0], qhA, rk0, h0);
    __builtin_amdgcn_sched_barrier(0);   // keep B-commit after compute A

    // ================= commit job B to buf1 ============================
    #pragma unroll
    for (int it = 0; it < 10; ++it) {
        const int jj = tid + it * 256;
        if (jj < NHALO * 4) {
            const int n = jj >> 2;
            const int c = jj & 3;
            const int hx = n / (HY * HZ);
            const int r  = n - hx * (HY * HZ);
            const int hy = r / HZ;
            uint2 w;
            w.x = pkbits(FB[it].x, FB[it].y);
            w.y = pkbits(FB[it].z, FB[it].w);
            ((uint2*)s_k[1])[((n * 2 + (c >> 1)) ^ (hy & 1)) * 2 + (c & 1)] = w;
        }
    }
    hh2 qhB[8];
    qhB[0] = asz(pkbits(QB0.x, QB0.y)); qhB[1] = asz(pkbits(QB0.z, QB0.w));
    qhB[2] = asz(pkbits(QB1.x, QB1.y)); qhB[3] = asz(pkbits(QB1.z, QB1.w));
    qhB[4] = asz(pkbits(QB2.x, QB2.y)); qhB[5] = asz(pkbits(QB2.z, QB2.w));
    qhB[6] = asz(pkbits(QB3.x, QB3.y)); qhB[7] = asz(pkbits(QB3.z, QB3.w));

    __syncthreads();

    // ================= compute job B ===================================
    compute(s_k[1], qhB, rk1, h1);
}

extern "C" void kernel_launch(void* const* d_in, const int* in_sizes, int n_in,
                              void* d_out, int out_size, void* d_ws, size_t ws_size,
                              hipStream_t stream) {
    const float* q   = (const float*)d_in[0];
    const float* k   = (const float*)d_in[1];
    const float* rpb = (const float*)d_in[2];
    float* out = (float*)d_out;

    natt_disp_kernel<<<GRID, 256, 0, stream>>>(q, k, rpb, out);
}

// Round 16
// 22.825 us; speedup vs baseline: 1.6976x; 1.6976x over previous
//
#include <hip/hip_runtime.h>

typedef _Float16 hh2 __attribute__((ext_vector_type(2)));

#define DH 40
#define DW 40
#define DT 40
#define NC 96
#define NH 6
#define HD 16
#define NTOK 27
#define NVOX (DH * DW * DT)

// Block = (8x4x8 tile, head-pair), 512 threads = 2 heads x 256 voxels.
// Per-thread work identical to R14 (one head, one voxel); the pair shares
// every 128B k/q cache line -> half the unique lines per head.
#define TX 8
#define TY 4
#define TZ 8
#define HX 10
#define HY 6
#define HZ 10
#define NHALO 600

#define NBLK 750              // 250 tiles x 3 pairs
#define GRID 752
#define PER_XCD 94

__device__ __forceinline__ float dot2acc(hh2 a, hh2 b, float c) {
    return __builtin_amdgcn_fdot2(a, b, c, false);
}
__device__ __forceinline__ unsigned int pkbits(float a, float b) {
    return __builtin_bit_cast(unsigned int, __builtin_amdgcn_cvt_pkrtz(a, b));
}
__device__ __forceinline__ hh2 asz(unsigned int u) {
    return __builtin_bit_cast(hh2, u);
}

union I4H {
    int4 v;
    hh2 h[4];
};

// LDS row per halo voxel = 64B (pair's 32 f16 channels) = 4x 16B chunks.
// Swizzle phys = (4n+m) ^ (n&7): bijective (n recoverable from high bits);
// for any read instr the 8 lz-lanes' slots = linear bijection of (n0,n1,n2)
// -> all 8 chunk-slots covered, 2 lanes/bank = conflict-free (m136).
__device__ __forceinline__ int swz(int n, int m) {
    return (4 * n + m) ^ (n & 7);
}

__global__ __launch_bounds__(512, 6) void natt_disp_kernel(
    const float* __restrict__ q,
    const float* __restrict__ k,
    const float* __restrict__ rpb,
    float* __restrict__ out)
{
    __shared__ int4 s_k[NHALO * 4];   // 38.4 KB

    // XCD swizzle: blockIdx round-robins XCDs; chunk job space per XCD.
    const int job = (blockIdx.x & 7) * PER_XCD + (blockIdx.x >> 3);
    if (job >= NBLK) return;   // block-uniform, before any sync

    const int hp   = job % 3;            // head pair: heads 2hp, 2hp+1
    const int tile = job / 3;
    const int tz = tile % 5;
    const int ty = (tile / 5) % 10;
    const int tx = tile / 50;
    const int x0 = tx * TX, y0 = ty * TY, z0 = tz * TZ;

    const int tid = threadIdx.x;
    const int v = tid & 255;             // voxel within tile
    const int p = tid >> 8;              // head within pair (wave-uniform)

    const int lz = v & 7;
    const int ly = (v >> 3) & 3;
    const int lx = v >> 5;
    const int vox = ((x0 + lx) * DW + (y0 + ly)) * DT + (z0 + lz);

    // ---- rpb for this thread's head (wave-uniform) -> SGPRs, LOG2E folded
    const float LOG2E = 1.44269504f;
    const int ps = __builtin_amdgcn_readfirstlane(p);
    const int h = 2 * hp + ps;
    float rk[NTOK];
    {
        const float* rb = rpb + h * NTOK;
        #pragma unroll
        for (int kk = 0; kk < NTOK; ++kk) rk[kk] = rb[kk] * LOG2E;
    }

    // ---- Stage k halo: 600 lines x 8 float4 chunks (full 128B line per
    //      pair) = 4800 jobs over 512 threads, 10 rounds.
    #pragma unroll
    for (int it = 0; it < 10; ++it) {
        const int jj = tid + it * 512;
        if (jj < NHALO * 8) {
            const int n = jj >> 3;       // halo voxel (line)
            const int c = jj & 7;        // float4 chunk of the 128B line
            const int hx = n / (HY * HZ);
            const int r  = n - hx * (HY * HZ);
            const int hy = r / HZ;
            const int hz = r - hy * HZ;
            const int gx = x0 - 1 + hx;
            const int gy = y0 - 1 + hy;
            const int gz = z0 - 1 + hz;
            uint2 w; w.x = 0u; w.y = 0u;
            if (((unsigned)gx < DH) & ((unsigned)gy < DW) & ((unsigned)gz < DT)) {
                const float4 a = *(const float4*)(
                    k + ((size_t)((gx * DW + gy) * DT + gz)) * NC
                      + hp * 32 + c * 4);
                w.x = pkbits(a.x, a.y);
                w.y = pkbits(a.z, a.w);
            }
            // 16B f16 chunk m = c>>1, 8B half = c&1
            ((uint2*)s_k)[swz(n, c >> 1) * 2 + (c & 1)] = w;
        }
    }

    // ---- q fragment direct: thread reads its own 64B slice; the pair
    //      thread on the other half hits the same 128B line.
    hh2 qh[8];
    {
        const float4* qs = (const float4*)(q + (size_t)vox * NC
                                             + hp * 32 + p * HD);
        const float4 a = qs[0], b = qs[1], c = qs[2], d = qs[3];
        qh[0] = asz(pkbits(a.x, a.y)); qh[1] = asz(pkbits(a.z, a.w));
        qh[2] = asz(pkbits(b.x, b.y)); qh[3] = asz(pkbits(b.z, b.w));
        qh[4] = asz(pkbits(c.x, c.y)); qh[5] = asz(pkbits(c.z, c.w));
        qh[6] = asz(pkbits(d.x, d.y)); qh[7] = asz(pkbits(d.z, d.w));
    }

    __syncthreads();

    // ---- fused: dot -> exp2 (no max; |logit|max ~5.6 << fp32 range) ----
    const float SC2 = 0.36067376f;   // 0.25 * LOG2E
    float sum = 0.f, sx = 0.f, sy = 0.f, sz = 0.f;

    #pragma unroll
    for (int i = 0; i < 3; ++i) {
        #pragma unroll
        for (int j = 0; j < 3; ++j) {
            const int base = ((lx + i) * HY + (ly + j)) * HZ + lz;
            #pragma unroll
            for (int ll = 0; ll < 3; ++ll) {
                const int n = base + ll;
                const int ph0 = swz(n, 2 * p);   // chunk 2p; 2p+1 = ph0^1
                I4H u0, u1;
                u0.v = s_k[ph0];
                u1.v = s_k[ph0 ^ 1];
                float d = 0.0f;
                d = dot2acc(qh[0], u0.h[0], d);
                d = dot2acc(qh[1], u0.h[1], d);
                d = dot2acc(qh[2], u0.h[2], d);
                d = dot2acc(qh[3], u0.h[3], d);
                d = dot2acc(qh[4], u1.h[0], d);
                d = dot2acc(qh[5], u1.h[1], d);
                d = dot2acc(qh[6], u1.h[2], d);
                d = dot2acc(qh[7], u1.h[3], d);
                const int kk = (i * 3 + j) * 3 + ll;
                const float t = exp2f(fmaf(d, SC2, rk[kk]));
                sum += t;
                if (i == 0) sx -= t; else if (i == 2) sx += t;
                if (j == 0) sy -= t; else if (j == 2) sy += t;
                if (ll == 0) sz -= t; else if (ll == 2) sz += t;
            }
        }
    }

    const float inv = __builtin_amdgcn_rcpf(sum);

    out[((size_t)(h * 3 + 0)) * NVOX + vox] = sx * inv;
    out[((size_t)(h * 3 + 1)) * NVOX + vox] = sy * inv;
    out[((size_t)(h * 3 + 2)) * NVOX + vox] = sz * inv;
}

extern "C" void kernel_launch(void* const* d_in, const int* in_sizes, int n_in,
                              void* d_out, int out_size, void* d_ws, size_t ws_size,
                              hipStream_t stream) {
    const float* q   = (const float*)d_in[0];
    const float* k   = (const float*)d_in[1];
    const float* rpb = (const float*)d_in[2];
    float* out = (float*)d_out;

    natt_disp_kernel<<<GRID, 512, 0, stream>>>(q, k, rpb, out);
}